// Round 5
// baseline (359.876 us; speedup 1.0000x reference)
//
#include <hip/hip_runtime.h>
#include <cstdint>

typedef __attribute__((ext_vector_type(8))) __bf16 bf16x8;
typedef __attribute__((ext_vector_type(4))) float f32x4;
typedef __attribute__((ext_vector_type(16))) float f32x16;
typedef __attribute__((ext_vector_type(4))) unsigned int u32x4;

#define DEV __device__ __forceinline__

DEV unsigned short f2bf(float f) {
    unsigned int u = __builtin_bit_cast(unsigned int, f);
    u += 0x7fffu + ((u >> 16) & 1u);   // RNE
    return (unsigned short)(u >> 16);
}

DEV void async_copy16(const void* g, void* l) {
    __builtin_amdgcn_global_load_lds(
        (const __attribute__((address_space(1))) unsigned int*)g,
        (__attribute__((address_space(3))) unsigned int*)l, 16, 0, 0);
}

DEV f32x4 mfma16(bf16x8 a, bf16x8 b, f32x4 c) {
    return __builtin_amdgcn_mfma_f32_16x16x32_bf16(a, b, c, 0, 0, 0);
}
DEV f32x16 mfma32(bf16x8 a, bf16x8 b, f32x16 c) {
    return __builtin_amdgcn_mfma_f32_32x32x16_bf16(a, b, c, 0, 0, 0);
}
DEV unsigned int cvtpk(float lo, float hi) {
    unsigned int d;
    asm("v_cvt_pk_bf16_f32 %0, %1, %2" : "=v"(d) : "v"(lo), "v"(hi));
    return d;
}
DEV float exp2f_fast(float x) { return __builtin_amdgcn_exp2f(x); }

// ---------------- f32 -> bf16 convert (vectorized) ----------------
__global__ __launch_bounds__(256) void convert_bf16(const float* __restrict__ in,
                                                    unsigned short* __restrict__ outp, int n) {
    int i = (blockIdx.x * 256 + threadIdx.x) * 4;
    if (i >= n) return;
    float4 v = *(const float4*)&in[i];
    ushort4 o;
    o.x = f2bf(v.x); o.y = f2bf(v.y); o.z = f2bf(v.z); o.w = f2bf(v.w);
    *(ushort4*)&outp[i] = o;
}

// ---------------- W[K][N] f32 -> Wt[N][K] bf16 ----------------
__global__ __launch_bounds__(256) void transpose_convert(const float* __restrict__ W,
                                                         unsigned short* __restrict__ Wt,
                                                         int K, int N) {
    __shared__ float tile[32][33];
    int n0 = blockIdx.x * 32, k0 = blockIdx.y * 32;
    int tx = threadIdx.x & 31, ty = threadIdx.x >> 5;  // ty 0..7
#pragma unroll
    for (int i = 0; i < 32; i += 8)
        tile[ty + i][tx] = W[(size_t)(k0 + ty + i) * N + n0 + tx];
    __syncthreads();
#pragma unroll
    for (int i = 0; i < 32; i += 8)
        Wt[(size_t)(n0 + ty + i) * K + k0 + tx] = f2bf(tile[tx][ty + i]);
}

// ---------------- V part of QKV -> Vt[b][h][d][s] (bf16 -> bf16) ----------------
__global__ __launch_bounds__(256) void transpose_v(const unsigned short* __restrict__ qkv,
                                                   unsigned short* __restrict__ vt) {
    constexpr int S = 2048, RS = 3072;
    __shared__ unsigned short tile[32][33];
    const int s0 = blockIdx.x * 32, d0 = blockIdx.y * 32, bh = blockIdx.z;
    const int b = bh >> 4, h = bh & 15;
    const int tx = threadIdx.x & 31, ty = threadIdx.x >> 5;  // ty 0..7
#pragma unroll
    for (int i = 0; i < 32; i += 8)
        tile[ty + i][tx] = qkv[(size_t)(b * S + s0 + ty + i) * RS + 2048 + h * 64 + d0 + tx];
    __syncthreads();
#pragma unroll
    for (int i = 0; i < 32; i += 8)
        vt[(size_t)(bh * 64 + d0 + ty + i) * S + s0 + tx] = tile[tx][ty + i];
}

// ---------------- GEMM: C[M][N] = A[M][K] @ Bt[N][K]^T + bias ----------------
template <int OUTF32>
__global__ __launch_bounds__(256) void gemm_bt(const unsigned short* __restrict__ A,
                                               const unsigned short* __restrict__ Bt,
                                               const float* __restrict__ bias,
                                               void* __restrict__ Cout,
                                               int M, int N, int K,
                                               int scaleN, float scaleV) {
    __shared__ __align__(16) unsigned short Asl[128][32];
    __shared__ __align__(16) unsigned short Bsl[128][32];
    const int tid = threadIdx.x;
    const int lane = tid & 63, w = tid >> 6;
    const int cl = lane & 15, kg = lane >> 4;
    const int m0 = blockIdx.x * 128, n0 = blockIdx.y * 128;
    const int wm = (w >> 1) * 64, wn = (w & 1) * 64;

    f32x4 acc[4][4] = {};

    const int rs = lane >> 2, ks = (lane & 3) * 8;
    const unsigned short* ga = A + (size_t)(m0 + w * 32 + rs) * K + ks;
    const unsigned short* gb = Bt + (size_t)(n0 + w * 32 + rs) * K + ks;
    unsigned short* la = &Asl[w * 32][0];
    unsigned short* lb = &Bsl[w * 32][0];

    for (int k0 = 0; k0 < K; k0 += 32) {
        async_copy16(ga, la);
        async_copy16(ga + (size_t)16 * K, la + 512);
        async_copy16(gb, lb);
        async_copy16(gb + (size_t)16 * K, lb + 512);
        ga += 32; gb += 32;
        __syncthreads();

        bf16x8 af[4], bfv[4];
#pragma unroll
        for (int mf = 0; mf < 4; ++mf)
            af[mf] = *(const bf16x8*)&Asl[wm + mf * 16 + cl][kg * 8];
#pragma unroll
        for (int nf = 0; nf < 4; ++nf)
            bfv[nf] = *(const bf16x8*)&Bsl[wn + nf * 16 + cl][kg * 8];
#pragma unroll
        for (int mf = 0; mf < 4; ++mf)
#pragma unroll
            for (int nf = 0; nf < 4; ++nf)
                acc[mf][nf] = mfma16(af[mf], bfv[nf], acc[mf][nf]);
        __syncthreads();
    }

#pragma unroll
    for (int mf = 0; mf < 4; ++mf) {
#pragma unroll
        for (int nf = 0; nf < 4; ++nf) {
            const int col = n0 + wn + nf * 16 + cl;
            const float bv = bias[col];
#pragma unroll
            for (int r = 0; r < 4; ++r) {
                const int row = m0 + wm + mf * 16 + kg * 4 + r;
                float v = acc[mf][nf][r] + bv;
                if (col < scaleN) v *= scaleV;
                if (OUTF32)
                    ((float*)Cout)[(size_t)row * N + col] = v;
                else
                    ((unsigned short*)Cout)[(size_t)row * N + col] = f2bf(v);
            }
        }
    }
}

// ---------------- flash attention v4b: split-KV, 2 waves/block ----------------
// grid (64, 32), block = 128 (2 waves). Each block: one 32-row q-strip; wave w
// handles half the key tiles; partials merged via LDS. All cross-lane ops are
// the R2-verified __shfl primitives. Q pre-scaled by 0.125*log2e (exp2 domain).
__global__ __launch_bounds__(128, 4) void attn_fwd4(const unsigned short* __restrict__ qkv,
                                                    const unsigned short* __restrict__ vt,
                                                    unsigned short* __restrict__ aout) {
    constexpr int S = 2048, RS = 3072;
    __shared__ float Mlds[64], Llds[64];
    __shared__ __align__(16) f32x4 Olds[64][8];
    const int tid = threadIdx.x;
    const int l = tid & 63, w = tid >> 6;
    const int q31 = l & 31, hi = l >> 5;
    const int bh = blockIdx.y, b = bh >> 4, h = bh & 15;
    const int strip = (int)gridDim.x - 1 - (int)blockIdx.x;   // heavy blocks first
    const int q0 = strip * 32;
    const int q = q0 + q31;
    const unsigned short* Qp = qkv + (size_t)b * S * RS + h * 64;
    const unsigned short* Kp = Qp + 1024;
    const unsigned short* Vtp = vt + (size_t)bh * 64 * S;

    bf16x8 qf[4];
#pragma unroll
    for (int kf = 0; kf < 4; ++kf)
        qf[kf] = *(const bf16x8*)&Qp[(size_t)q * RS + kf * 16 + hi * 8];

    float m = -1e30f, lsum = 0.f;
    f32x16 oacc[2] = {};

    const int T = ((q0 + 31) >> 6) + 1;       // # 64-key tiles for this strip
    const int t0 = w ? (T >> 1) : 0;
    const int t1 = w ? T : (T >> 1);

    if (t0 < t1) {
        // prologue: first K tile
        bf16x8 kb[2][4];
#pragma unroll
        for (int kt = 0; kt < 2; ++kt)
#pragma unroll
            for (int kf = 0; kf < 4; ++kf)
                kb[kt][kf] = *(const bf16x8*)&Kp[(size_t)(t0 * 64 + kt * 32 + q31) * RS + kf * 16 + hi * 8];

        for (int t = t0; t < t1; ++t) {
            const int s0 = t * 64;
            // V frags (issued early, consumed after softmax)
            bf16x8 vb[2][4];
#pragma unroll
            for (int df = 0; df < 2; ++df)
#pragma unroll
                for (int ks = 0; ks < 4; ++ks)
                    vb[df][ks] = *(const bf16x8*)&Vtp[(size_t)(df * 32 + q31) * S + s0 + ks * 16 + hi * 8];

            // ---- T[key][q] = K @ Q^T (swapped) ----
            f32x16 tacc[2] = {};
            __builtin_amdgcn_s_setprio(1);
#pragma unroll
            for (int kt = 0; kt < 2; ++kt)
#pragma unroll
                for (int kf = 0; kf < 4; ++kf)
                    tacc[kt] = mfma32(kb[kt][kf], qf[kf], tacc[kt]);
            __builtin_amdgcn_s_setprio(0);

            // prefetch next K tile
            if (t + 1 < t1) {
#pragma unroll
                for (int kt = 0; kt < 2; ++kt)
#pragma unroll
                    for (int kf = 0; kf < 4; ++kf)
                        kb[kt][kf] = *(const bf16x8*)&Kp[(size_t)((t + 1) * 64 + kt * 32 + q31) * RS + kf * 16 + hi * 8];
            }

            // ---- causal mask (lane owns q-row l&31; keys in-lane) ----
            const bool partial = (s0 + 63 > q0);
            float pv[2][16];
#pragma unroll
            for (int kt = 0; kt < 2; ++kt)
#pragma unroll
                for (int r = 0; r < 16; ++r) {
                    const int key = s0 + kt * 32 + (r & 3) + ((r >> 2) << 3) + hi * 4;
                    float sv = tacc[kt][r];
                    if (partial && key > q) sv = -1e30f;
                    pv[kt][r] = sv;
                }

            // ---- row max: in-lane tree + one half-swap (R2-verified shfl) ----
            float rx = pv[0][0];
#pragma unroll
            for (int kt = 0; kt < 2; ++kt)
#pragma unroll
                for (int r = 0; r < 16; ++r) rx = fmaxf(rx, pv[kt][r]);
            rx = fmaxf(rx, __shfl_xor(rx, 32, 64));

            // ---- defer-max rescale (THR = 8*log2e) ----
            if (__any(rx - m > 11.5f)) {
                const float mn = fmaxf(m, rx);
                const float alpha = exp2f_fast(m - mn);
                lsum *= alpha;
                m = mn;
#pragma unroll
                for (int r = 0; r < 16; ++r) {
                    const float ar = __shfl(alpha, (r & 3) + ((r >> 2) << 3) + hi * 4, 64);
                    oacc[0][r] *= ar;
                    oacc[1][r] *= ar;
                }
            }

            // ---- exp2 + pack + row sum ----
            unsigned int pk[2][4][2];
            float rsum = 0.f;
#pragma unroll
            for (int kt = 0; kt < 2; ++kt)
#pragma unroll
                for (int g = 0; g < 4; ++g) {
                    const float e0 = exp2f_fast(pv[kt][g * 4 + 0] - m);
                    const float e1 = exp2f_fast(pv[kt][g * 4 + 1] - m);
                    const float e2 = exp2f_fast(pv[kt][g * 4 + 2] - m);
                    const float e3 = exp2f_fast(pv[kt][g * 4 + 3] - m);
                    pk[kt][g][0] = cvtpk(e0, e1);
                    pk[kt][g][1] = cvtpk(e2, e3);
                    rsum += (e0 + e1) + (e2 + e3);
                }
            rsum += __shfl_xor(rsum, 32, 64);
            lsum += rsum;

            // ---- PV: R2-verified select-based PA assembly (shfl half-swap) ----
#pragma unroll
            for (int ks = 0; ks < 4; ++ks) {
                const int kt = ks >> 1, kslo = ks & 1;
                const unsigned int pkA0 = pk[kt][2 * kslo][0],     pkA1 = pk[kt][2 * kslo][1];
                const unsigned int pkB0 = pk[kt][2 * kslo + 1][0], pkB1 = pk[kt][2 * kslo + 1][1];
                const unsigned int send0 = hi ? pkA0 : pkB0;
                const unsigned int send1 = hi ? pkA1 : pkB1;
                const unsigned int own0  = hi ? pkB0 : pkA0;
                const unsigned int own1  = hi ? pkB1 : pkA1;
                const unsigned int recv0 = (unsigned int)__shfl_xor((int)send0, 32, 64);
                const unsigned int recv1 = (unsigned int)__shfl_xor((int)send1, 32, 64);
                u32x4 u;
                u[0] = hi ? recv0 : own0;
                u[1] = hi ? recv1 : own1;
                u[2] = hi ? own0 : recv0;
                u[3] = hi ? own1 : recv1;
                const bf16x8 pa = __builtin_bit_cast(bf16x8, u);
                __builtin_amdgcn_s_setprio(1);
                oacc[0] = mfma32(pa, vb[0][ks], oacc[0]);
                oacc[1] = mfma32(pa, vb[1][ks], oacc[1]);
                __builtin_amdgcn_s_setprio(0);
            }
        }
    }

    // ---- merge partials: wave1 -> LDS, wave0 combines & writes ----
    if (w == 1) {
        Mlds[l] = m;
        Llds[l] = lsum;
#pragma unroll
        for (int g = 0; g < 4; ++g) {
            Olds[l][g]     = f32x4{oacc[0][g * 4 + 0], oacc[0][g * 4 + 1], oacc[0][g * 4 + 2], oacc[0][g * 4 + 3]};
            Olds[l][g + 4] = f32x4{oacc[1][g * 4 + 0], oacc[1][g * 4 + 1], oacc[1][g * 4 + 2], oacc[1][g * 4 + 3]};
        }
    }
    __syncthreads();
    if (w == 1) return;

    const float m1 = Mlds[l];
    const float l1 = Llds[l];
    const float mn = fmaxf(m, m1);
    const float a0 = exp2f_fast(m - mn);
    const float a1 = exp2f_fast(m1 - mn);
    const float lm = lsum * a0 + l1 * a1;
    const float linv = 1.f / lm;

#pragma unroll
    for (int r = 0; r < 16; ++r) {
        const int qrow = (r & 3) + ((r >> 2) << 3) + hi * 4;
        const float a0r = __shfl(a0, qrow, 64);
        const float a1r = __shfl(a1, qrow, 64);
        const float lr = __shfl(linv, qrow, 64);
        const int g = r >> 2, e = r & 3;
        const float o0 = oacc[0][r] * a0r + Olds[l][g][e] * a1r;
        const float o1 = oacc[1][r] * a0r + Olds[l][g + 4][e] * a1r;
        const int row = q0 + qrow;
        aout[(size_t)(b * S + row) * 1024 + h * 64 + q31]      = f2bf(o0 * lr);
        aout[(size_t)(b * S + row) * 1024 + h * 64 + 32 + q31] = f2bf(o1 * lr);
    }
}

extern "C" void kernel_launch(void* const* d_in, const int* in_sizes, int n_in,
                              void* d_out, int out_size, void* d_ws, size_t ws_size,
                              hipStream_t stream) {
    (void)in_sizes; (void)n_in; (void)out_size; (void)ws_size;
    const float* hs    = (const float*)d_in[0];  // [2,2048,1024]
    const float* wqkv  = (const float*)d_in[1];  // [1024,3072]
    const float* bqkv  = (const float*)d_in[2];  // [3072]
    const float* wproj = (const float*)d_in[3];  // [1024,1024]
    const float* bproj = (const float*)d_in[4];  // [1024]
    float* out = (float*)d_out;                  // [2,2048,1024] f32

    unsigned short* Xb  = (unsigned short*)d_ws;                 // 4096*1024 (reused as Vt)
    unsigned short* Wqt = Xb  + (size_t)4096 * 1024;             // 3072*1024
    unsigned short* Wpt = Wqt + (size_t)3072 * 1024;             // 1024*1024
    unsigned short* QKV = Wpt + (size_t)1024 * 1024;             // 4096*3072
    unsigned short* AO  = QKV + (size_t)4096 * 3072;             // 4096*1024
    unsigned short* Vt  = Xb;  // X dead after QKV GEMM; Vt = [32 bh][64 d][2048 s]

    const float qscale = 0.125f * 1.4426950408889634f;  // fold softmax scale + log2e into Q

    convert_bf16<<<4096, 256, 0, stream>>>(hs, Xb, 4096 * 1024);
    transpose_convert<<<dim3(3072 / 32, 1024 / 32), 256, 0, stream>>>(wqkv, Wqt, 1024, 3072);
    transpose_convert<<<dim3(1024 / 32, 1024 / 32), 256, 0, stream>>>(wproj, Wpt, 1024, 1024);

    gemm_bt<0><<<dim3(32, 24), 256, 0, stream>>>(Xb, Wqt, bqkv, (void*)QKV, 4096, 3072, 1024,
                                                 1024, qscale);
    transpose_v<<<dim3(64, 2, 32), 256, 0, stream>>>(QKV, Vt);
    attn_fwd4<<<dim3(64, 32), 128, 0, stream>>>(QKV, Vt, AO);
    gemm_bt<1><<<dim3(32, 8), 256, 0, stream>>>(AO, Wpt, bproj, (void*)out, 4096, 1024, 1024,
                                                0, 1.0f);
}

// Round 6
// 192.314 us; speedup vs baseline: 1.8713x; 1.8713x over previous
//
#include <hip/hip_runtime.h>
#include <cstdint>

typedef __attribute__((ext_vector_type(8))) __bf16 bf16x8;
typedef __attribute__((ext_vector_type(4))) float f32x4;
typedef __attribute__((ext_vector_type(16))) float f32x16;
typedef __attribute__((ext_vector_type(4))) unsigned int u32x4;

#define DEV __device__ __forceinline__

DEV unsigned short f2bf(float f) {
    unsigned int u = __builtin_bit_cast(unsigned int, f);
    u += 0x7fffu + ((u >> 16) & 1u);   // RNE
    return (unsigned short)(u >> 16);
}

DEV void async_copy16(const void* g, void* l) {
    __builtin_amdgcn_global_load_lds(
        (const __attribute__((address_space(1))) unsigned int*)g,
        (__attribute__((address_space(3))) unsigned int*)l, 16, 0, 0);
}

DEV f32x4 mfma16(bf16x8 a, bf16x8 b, f32x4 c) {
    return __builtin_amdgcn_mfma_f32_16x16x32_bf16(a, b, c, 0, 0, 0);
}
DEV f32x16 mfma32(bf16x8 a, bf16x8 b, f32x16 c) {
    return __builtin_amdgcn_mfma_f32_32x32x16_bf16(a, b, c, 0, 0, 0);
}
DEV unsigned int cvtpk(float lo, float hi) {
    unsigned int d;
    asm("v_cvt_pk_bf16_f32 %0, %1, %2" : "=v"(d) : "v"(lo), "v"(hi));
    return d;
}
DEV float exp2f_fast(float x) { return __builtin_amdgcn_exp2f(x); }

// ---------------- f32 -> bf16 convert (vectorized) ----------------
__global__ __launch_bounds__(256) void convert_bf16(const float* __restrict__ in,
                                                    unsigned short* __restrict__ outp, int n) {
    int i = (blockIdx.x * 256 + threadIdx.x) * 4;
    if (i >= n) return;
    float4 v = *(const float4*)&in[i];
    ushort4 o;
    o.x = f2bf(v.x); o.y = f2bf(v.y); o.z = f2bf(v.z); o.w = f2bf(v.w);
    *(ushort4*)&outp[i] = o;
}

// ---------------- W[K][N] f32 -> Wt[N][K] bf16 ----------------
__global__ __launch_bounds__(256) void transpose_convert(const float* __restrict__ W,
                                                         unsigned short* __restrict__ Wt,
                                                         int K, int N) {
    __shared__ float tile[32][33];
    int n0 = blockIdx.x * 32, k0 = blockIdx.y * 32;
    int tx = threadIdx.x & 31, ty = threadIdx.x >> 5;  // ty 0..7
#pragma unroll
    for (int i = 0; i < 32; i += 8)
        tile[ty + i][tx] = W[(size_t)(k0 + ty + i) * N + n0 + tx];
    __syncthreads();
#pragma unroll
    for (int i = 0; i < 32; i += 8)
        Wt[(size_t)(n0 + ty + i) * K + k0 + tx] = f2bf(tile[tx][ty + i]);
}

// ---------------- V part of QKV -> Vt[b][h][d][s] (bf16 -> bf16) ----------------
__global__ __launch_bounds__(256) void transpose_v(const unsigned short* __restrict__ qkv,
                                                   unsigned short* __restrict__ vt) {
    constexpr int S = 2048, RS = 3072;
    __shared__ unsigned short tile[32][33];
    const int s0 = blockIdx.x * 32, d0 = blockIdx.y * 32, bh = blockIdx.z;
    const int b = bh >> 4, h = bh & 15;
    const int tx = threadIdx.x & 31, ty = threadIdx.x >> 5;  // ty 0..7
#pragma unroll
    for (int i = 0; i < 32; i += 8)
        tile[ty + i][tx] = qkv[(size_t)(b * S + s0 + ty + i) * RS + 2048 + h * 64 + d0 + tx];
    __syncthreads();
#pragma unroll
    for (int i = 0; i < 32; i += 8)
        vt[(size_t)(bh * 64 + d0 + ty + i) * S + s0 + tx] = tile[tx][ty + i];
}

// ---------------- GEMM: C[M][N] = A[M][K] @ Bt[N][K]^T + bias ----------------
template <int OUTF32>
__global__ __launch_bounds__(256) void gemm_bt(const unsigned short* __restrict__ A,
                                               const unsigned short* __restrict__ Bt,
                                               const float* __restrict__ bias,
                                               void* __restrict__ Cout,
                                               int M, int N, int K,
                                               int scaleN, float scaleV) {
    __shared__ __align__(16) unsigned short Asl[128][32];
    __shared__ __align__(16) unsigned short Bsl[128][32];
    const int tid = threadIdx.x;
    const int lane = tid & 63, w = tid >> 6;
    const int cl = lane & 15, kg = lane >> 4;
    const int m0 = blockIdx.x * 128, n0 = blockIdx.y * 128;
    const int wm = (w >> 1) * 64, wn = (w & 1) * 64;

    f32x4 acc[4][4] = {};

    const int rs = lane >> 2, ks = (lane & 3) * 8;
    const unsigned short* ga = A + (size_t)(m0 + w * 32 + rs) * K + ks;
    const unsigned short* gb = Bt + (size_t)(n0 + w * 32 + rs) * K + ks;
    unsigned short* la = &Asl[w * 32][0];
    unsigned short* lb = &Bsl[w * 32][0];

    for (int k0 = 0; k0 < K; k0 += 32) {
        async_copy16(ga, la);
        async_copy16(ga + (size_t)16 * K, la + 512);
        async_copy16(gb, lb);
        async_copy16(gb + (size_t)16 * K, lb + 512);
        ga += 32; gb += 32;
        __syncthreads();

        bf16x8 af[4], bfv[4];
#pragma unroll
        for (int mf = 0; mf < 4; ++mf)
            af[mf] = *(const bf16x8*)&Asl[wm + mf * 16 + cl][kg * 8];
#pragma unroll
        for (int nf = 0; nf < 4; ++nf)
            bfv[nf] = *(const bf16x8*)&Bsl[wn + nf * 16 + cl][kg * 8];
#pragma unroll
        for (int mf = 0; mf < 4; ++mf)
#pragma unroll
            for (int nf = 0; nf < 4; ++nf)
                acc[mf][nf] = mfma16(af[mf], bfv[nf], acc[mf][nf]);
        __syncthreads();
    }

#pragma unroll
    for (int mf = 0; mf < 4; ++mf) {
#pragma unroll
        for (int nf = 0; nf < 4; ++nf) {
            const int col = n0 + wn + nf * 16 + cl;
            const float bv = bias[col];
#pragma unroll
            for (int r = 0; r < 4; ++r) {
                const int row = m0 + wm + mf * 16 + kg * 4 + r;
                float v = acc[mf][nf][r] + bv;
                if (col < scaleN) v *= scaleV;
                if (OUTF32)
                    ((float*)Cout)[(size_t)row * N + col] = v;
                else
                    ((unsigned short*)Cout)[(size_t)row * N + col] = f2bf(v);
            }
        }
    }
}

// ---------------- flash attention v5: split-KV, 2 waves/block ----------------
// grid (64, 32), block = 128 (2 waves). Each block: one 32-row q-strip; wave w
// handles half the key tiles; partials merged via LDS.
// NOTE: no min-occupancy launch_bounds arg — with a 2-wave block hipcc treats
// it as blocks/EU and caps VGPR at 64 -> catastrophic spill (R4: 349MB fetch).
// Natural allocation ~124 VGPR < 128 already gives 4 waves/SIMD.
__global__ __launch_bounds__(128) void attn_fwd4(const unsigned short* __restrict__ qkv,
                                                 const unsigned short* __restrict__ vt,
                                                 unsigned short* __restrict__ aout) {
    constexpr int S = 2048, RS = 3072;
    __shared__ float Mlds[64], Llds[64];
    __shared__ __align__(16) f32x4 Olds[64][8];
    const int tid = threadIdx.x;
    const int l = tid & 63, w = tid >> 6;
    const int q31 = l & 31, hi = l >> 5;
    const int bh = blockIdx.y, b = bh >> 4, h = bh & 15;
    const int strip = (int)gridDim.x - 1 - (int)blockIdx.x;   // heavy blocks first
    const int q0 = strip * 32;
    const int q = q0 + q31;
    const unsigned short* Qp = qkv + (size_t)b * S * RS + h * 64;
    const unsigned short* Kp = Qp + 1024;
    const unsigned short* Vtp = vt + (size_t)bh * 64 * S;

    bf16x8 qf[4];
#pragma unroll
    for (int kf = 0; kf < 4; ++kf)
        qf[kf] = *(const bf16x8*)&Qp[(size_t)q * RS + kf * 16 + hi * 8];

    float m = -1e30f, lsum = 0.f;
    f32x16 oacc[2] = {};

    const int T = ((q0 + 31) >> 6) + 1;       // # 64-key tiles for this strip
    const int t0 = w ? (T >> 1) : 0;
    const int t1 = w ? T : (T >> 1);

    if (t0 < t1) {
        // prologue: first K tile
        bf16x8 kb[2][4];
#pragma unroll
        for (int kt = 0; kt < 2; ++kt)
#pragma unroll
            for (int kf = 0; kf < 4; ++kf)
                kb[kt][kf] = *(const bf16x8*)&Kp[(size_t)(t0 * 64 + kt * 32 + q31) * RS + kf * 16 + hi * 8];

        for (int t = t0; t < t1; ++t) {
            const int s0 = t * 64;
            // V frags (issued early, consumed after softmax)
            bf16x8 vb[2][4];
#pragma unroll
            for (int df = 0; df < 2; ++df)
#pragma unroll
                for (int ks = 0; ks < 4; ++ks)
                    vb[df][ks] = *(const bf16x8*)&Vtp[(size_t)(df * 32 + q31) * S + s0 + ks * 16 + hi * 8];

            // ---- T[key][q] = K @ Q^T (swapped) ----
            f32x16 tacc[2] = {};
            __builtin_amdgcn_s_setprio(1);
#pragma unroll
            for (int kt = 0; kt < 2; ++kt)
#pragma unroll
                for (int kf = 0; kf < 4; ++kf)
                    tacc[kt] = mfma32(kb[kt][kf], qf[kf], tacc[kt]);
            __builtin_amdgcn_s_setprio(0);

            // prefetch next K tile
            if (t + 1 < t1) {
#pragma unroll
                for (int kt = 0; kt < 2; ++kt)
#pragma unroll
                    for (int kf = 0; kf < 4; ++kf)
                        kb[kt][kf] = *(const bf16x8*)&Kp[(size_t)((t + 1) * 64 + kt * 32 + q31) * RS + kf * 16 + hi * 8];
            }

            // ---- causal mask (lane owns q-row l&31; keys in-lane) ----
            const bool partial = (s0 + 63 > q0);
            float pv[2][16];
#pragma unroll
            for (int kt = 0; kt < 2; ++kt)
#pragma unroll
                for (int r = 0; r < 16; ++r) {
                    const int key = s0 + kt * 32 + (r & 3) + ((r >> 2) << 3) + hi * 4;
                    float sv = tacc[kt][r];
                    if (partial && key > q) sv = -1e30f;
                    pv[kt][r] = sv;
                }

            // ---- row max: in-lane tree + one half-swap ----
            float rx = pv[0][0];
#pragma unroll
            for (int kt = 0; kt < 2; ++kt)
#pragma unroll
                for (int r = 0; r < 16; ++r) rx = fmaxf(rx, pv[kt][r]);
            rx = fmaxf(rx, __shfl_xor(rx, 32, 64));

            // ---- defer-max rescale (THR = 8*log2e) ----
            if (__any(rx - m > 11.5f)) {
                const float mn = fmaxf(m, rx);
                const float alpha = exp2f_fast(m - mn);
                lsum *= alpha;
                m = mn;
#pragma unroll
                for (int r = 0; r < 16; ++r) {
                    const float ar = __shfl(alpha, (r & 3) + ((r >> 2) << 3) + hi * 4, 64);
                    oacc[0][r] *= ar;
                    oacc[1][r] *= ar;
                }
            }

            // ---- exp2 + pack + row sum ----
            unsigned int pk[2][4][2];
            float rsum = 0.f;
#pragma unroll
            for (int kt = 0; kt < 2; ++kt)
#pragma unroll
                for (int g = 0; g < 4; ++g) {
                    const float e0 = exp2f_fast(pv[kt][g * 4 + 0] - m);
                    const float e1 = exp2f_fast(pv[kt][g * 4 + 1] - m);
                    const float e2 = exp2f_fast(pv[kt][g * 4 + 2] - m);
                    const float e3 = exp2f_fast(pv[kt][g * 4 + 3] - m);
                    pk[kt][g][0] = cvtpk(e0, e1);
                    pk[kt][g][1] = cvtpk(e2, e3);
                    rsum += (e0 + e1) + (e2 + e3);
                }
            rsum += __shfl_xor(rsum, 32, 64);
            lsum += rsum;

            // ---- PV: select-based PA assembly (shfl half-swap, R2-verified) ----
#pragma unroll
            for (int ks = 0; ks < 4; ++ks) {
                const int kt = ks >> 1, kslo = ks & 1;
                const unsigned int pkA0 = pk[kt][2 * kslo][0],     pkA1 = pk[kt][2 * kslo][1];
                const unsigned int pkB0 = pk[kt][2 * kslo + 1][0], pkB1 = pk[kt][2 * kslo + 1][1];
                const unsigned int send0 = hi ? pkA0 : pkB0;
                const unsigned int send1 = hi ? pkA1 : pkB1;
                const unsigned int own0  = hi ? pkB0 : pkA0;
                const unsigned int own1  = hi ? pkB1 : pkA1;
                const unsigned int recv0 = (unsigned int)__shfl_xor((int)send0, 32, 64);
                const unsigned int recv1 = (unsigned int)__shfl_xor((int)send1, 32, 64);
                u32x4 u;
                u[0] = hi ? recv0 : own0;
                u[1] = hi ? recv1 : own1;
                u[2] = hi ? own0 : recv0;
                u[3] = hi ? own1 : recv1;
                const bf16x8 pa = __builtin_bit_cast(bf16x8, u);
                __builtin_amdgcn_s_setprio(1);
                oacc[0] = mfma32(pa, vb[0][ks], oacc[0]);
                oacc[1] = mfma32(pa, vb[1][ks], oacc[1]);
                __builtin_amdgcn_s_setprio(0);
            }
        }
    }

    // ---- merge partials: wave1 -> LDS, wave0 combines & writes ----
    if (w == 1) {
        Mlds[l] = m;
        Llds[l] = lsum;
#pragma unroll
        for (int g = 0; g < 4; ++g) {
            Olds[l][g]     = f32x4{oacc[0][g * 4 + 0], oacc[0][g * 4 + 1], oacc[0][g * 4 + 2], oacc[0][g * 4 + 3]};
            Olds[l][g + 4] = f32x4{oacc[1][g * 4 + 0], oacc[1][g * 4 + 1], oacc[1][g * 4 + 2], oacc[1][g * 4 + 3]};
        }
    }
    __syncthreads();
    if (w == 1) return;

    const float m1 = Mlds[l];
    const float l1 = Llds[l];
    const float mn = fmaxf(m, m1);
    const float a0 = exp2f_fast(m - mn);
    const float a1 = exp2f_fast(m1 - mn);
    const float lm = lsum * a0 + l1 * a1;
    const float linv = 1.f / lm;

#pragma unroll
    for (int r = 0; r < 16; ++r) {
        const int qrow = (r & 3) + ((r >> 2) << 3) + hi * 4;
        const float a0r = __shfl(a0, qrow, 64);
        const float a1r = __shfl(a1, qrow, 64);
        const float lr = __shfl(linv, qrow, 64);
        const int g = r >> 2, e = r & 3;
        const float o0 = oacc[0][r] * a0r + Olds[l][g][e] * a1r;
        const float o1 = oacc[1][r] * a0r + Olds[l][g + 4][e] * a1r;
        const int row = q0 + qrow;
        aout[(size_t)(b * S + row) * 1024 + h * 64 + q31]      = f2bf(o0 * lr);
        aout[(size_t)(b * S + row) * 1024 + h * 64 + 32 + q31] = f2bf(o1 * lr);
    }
}

extern "C" void kernel_launch(void* const* d_in, const int* in_sizes, int n_in,
                              void* d_out, int out_size, void* d_ws, size_t ws_size,
                              hipStream_t stream) {
    (void)in_sizes; (void)n_in; (void)out_size; (void)ws_size;
    const float* hs    = (const float*)d_in[0];  // [2,2048,1024]
    const float* wqkv  = (const float*)d_in[1];  // [1024,3072]
    const float* bqkv  = (const float*)d_in[2];  // [3072]
    const float* wproj = (const float*)d_in[3];  // [1024,1024]
    const float* bproj = (const float*)d_in[4];  // [1024]
    float* out = (float*)d_out;                  // [2,2048,1024] f32

    unsigned short* Xb  = (unsigned short*)d_ws;                 // 4096*1024 (reused as Vt)
    unsigned short* Wqt = Xb  + (size_t)4096 * 1024;             // 3072*1024
    unsigned short* Wpt = Wqt + (size_t)3072 * 1024;             // 1024*1024
    unsigned short* QKV = Wpt + (size_t)1024 * 1024;             // 4096*3072
    unsigned short* AO  = QKV + (size_t)4096 * 3072;             // 4096*1024
    unsigned short* Vt  = Xb;  // X dead after QKV GEMM; Vt = [32 bh][64 d][2048 s]

    const float qscale = 0.125f * 1.4426950408889634f;  // fold softmax scale + log2e into Q

    convert_bf16<<<4096, 256, 0, stream>>>(hs, Xb, 4096 * 1024);
    transpose_convert<<<dim3(3072 / 32, 1024 / 32), 256, 0, stream>>>(wqkv, Wqt, 1024, 3072);
    transpose_convert<<<dim3(1024 / 32, 1024 / 32), 256, 0, stream>>>(wproj, Wpt, 1024, 1024);

    gemm_bt<0><<<dim3(32, 24), 256, 0, stream>>>(Xb, Wqt, bqkv, (void*)QKV, 4096, 3072, 1024,
                                                 1024, qscale);
    transpose_v<<<dim3(64, 2, 32), 256, 0, stream>>>(QKV, Vt);
    attn_fwd4<<<dim3(64, 32), 128, 0, stream>>>(QKV, Vt, AO);
    gemm_bt<1><<<dim3(32, 8), 256, 0, stream>>>(AO, Wpt, bproj, (void*)out, 4096, 1024, 1024,
                                                0, 1.0f);
}

// Round 8
// 160.511 us; speedup vs baseline: 2.2421x; 1.1981x over previous
//
#include <hip/hip_runtime.h>
#include <cstdint>

typedef __attribute__((ext_vector_type(8))) __bf16 bf16x8;
typedef __attribute__((ext_vector_type(4))) float f32x4;
typedef __attribute__((ext_vector_type(16))) float f32x16;
typedef __attribute__((ext_vector_type(4))) unsigned int u32x4;

#define DEV __device__ __forceinline__

DEV unsigned short f2bf(float f) {
    unsigned int u = __builtin_bit_cast(unsigned int, f);
    u += 0x7fffu + ((u >> 16) & 1u);   // RNE
    return (unsigned short)(u >> 16);
}

DEV void async_copy16(const void* g, void* l) {
    __builtin_amdgcn_global_load_lds(
        (const __attribute__((address_space(1))) unsigned int*)g,
        (__attribute__((address_space(3))) unsigned int*)l, 16, 0, 0);
}

DEV f32x4 mfma16(bf16x8 a, bf16x8 b, f32x4 c) {
    return __builtin_amdgcn_mfma_f32_16x16x32_bf16(a, b, c, 0, 0, 0);
}
DEV f32x16 mfma32(bf16x8 a, bf16x8 b, f32x16 c) {
    return __builtin_amdgcn_mfma_f32_32x32x16_bf16(a, b, c, 0, 0, 0);
}
DEV unsigned int cvtpk(float lo, float hi) {
    unsigned int d;
    asm("v_cvt_pk_bf16_f32 %0, %1, %2" : "=v"(d) : "v"(lo), "v"(hi));
    return d;
}
DEV float exp2f_fast(float x) { return __builtin_amdgcn_exp2f(x); }

// ---------------- f32 -> bf16 convert (vectorized) ----------------
__global__ __launch_bounds__(256) void convert_bf16(const float* __restrict__ in,
                                                    unsigned short* __restrict__ outp, int n) {
    int i = (blockIdx.x * 256 + threadIdx.x) * 4;
    if (i >= n) return;
    float4 v = *(const float4*)&in[i];
    ushort4 o;
    o.x = f2bf(v.x); o.y = f2bf(v.y); o.z = f2bf(v.z); o.w = f2bf(v.w);
    *(ushort4*)&outp[i] = o;
}

// ---------------- W[K][N] f32 -> Wt[N][K] bf16 ----------------
__global__ __launch_bounds__(256) void transpose_convert(const float* __restrict__ W,
                                                         unsigned short* __restrict__ Wt,
                                                         int K, int N) {
    __shared__ float tile[32][33];
    int n0 = blockIdx.x * 32, k0 = blockIdx.y * 32;
    int tx = threadIdx.x & 31, ty = threadIdx.x >> 5;  // ty 0..7
#pragma unroll
    for (int i = 0; i < 32; i += 8)
        tile[ty + i][tx] = W[(size_t)(k0 + ty + i) * N + n0 + tx];
    __syncthreads();
#pragma unroll
    for (int i = 0; i < 32; i += 8)
        Wt[(size_t)(n0 + ty + i) * K + k0 + tx] = f2bf(tile[tx][ty + i]);
}

// ---------------- V part of QKV -> Vt[b][h][d][s] (bf16 -> bf16) ----------------
__global__ __launch_bounds__(256) void transpose_v(const unsigned short* __restrict__ qkv,
                                                   unsigned short* __restrict__ vt) {
    constexpr int S = 2048, RS = 3072;
    __shared__ unsigned short tile[32][33];
    const int s0 = blockIdx.x * 32, d0 = blockIdx.y * 32, bh = blockIdx.z;
    const int b = bh >> 4, h = bh & 15;
    const int tx = threadIdx.x & 31, ty = threadIdx.x >> 5;  // ty 0..7
#pragma unroll
    for (int i = 0; i < 32; i += 8)
        tile[ty + i][tx] = qkv[(size_t)(b * S + s0 + ty + i) * RS + 2048 + h * 64 + d0 + tx];
    __syncthreads();
#pragma unroll
    for (int i = 0; i < 32; i += 8)
        vt[(size_t)(bh * 64 + d0 + ty + i) * S + s0 + tx] = tile[tx][ty + i];
}

// ---------------- GEMM: C[M][N] = A[M][K] @ Bt[N][K]^T + bias ----------------
template <int OUTF32>
__global__ __launch_bounds__(256) void gemm_bt(const unsigned short* __restrict__ A,
                                               const unsigned short* __restrict__ Bt,
                                               const float* __restrict__ bias,
                                               void* __restrict__ Cout,
                                               int M, int N, int K,
                                               int scaleN, float scaleV) {
    __shared__ __align__(16) unsigned short Asl[128][32];
    __shared__ __align__(16) unsigned short Bsl[128][32];
    const int tid = threadIdx.x;
    const int lane = tid & 63, w = tid >> 6;
    const int cl = lane & 15, kg = lane >> 4;
    const int m0 = blockIdx.x * 128, n0 = blockIdx.y * 128;
    const int wm = (w >> 1) * 64, wn = (w & 1) * 64;

    f32x4 acc[4][4] = {};

    const int rs = lane >> 2, ks = (lane & 3) * 8;
    const unsigned short* ga = A + (size_t)(m0 + w * 32 + rs) * K + ks;
    const unsigned short* gb = Bt + (size_t)(n0 + w * 32 + rs) * K + ks;
    unsigned short* la = &Asl[w * 32][0];
    unsigned short* lb = &Bsl[w * 32][0];

    for (int k0 = 0; k0 < K; k0 += 32) {
        async_copy16(ga, la);
        async_copy16(ga + (size_t)16 * K, la + 512);
        async_copy16(gb, lb);
        async_copy16(gb + (size_t)16 * K, lb + 512);
        ga += 32; gb += 32;
        __syncthreads();

        bf16x8 af[4], bfv[4];
#pragma unroll
        for (int mf = 0; mf < 4; ++mf)
            af[mf] = *(const bf16x8*)&Asl[wm + mf * 16 + cl][kg * 8];
#pragma unroll
        for (int nf = 0; nf < 4; ++nf)
            bfv[nf] = *(const bf16x8*)&Bsl[wn + nf * 16 + cl][kg * 8];
#pragma unroll
        for (int mf = 0; mf < 4; ++mf)
#pragma unroll
            for (int nf = 0; nf < 4; ++nf)
                acc[mf][nf] = mfma16(af[mf], bfv[nf], acc[mf][nf]);
        __syncthreads();
    }

#pragma unroll
    for (int mf = 0; mf < 4; ++mf) {
#pragma unroll
        for (int nf = 0; nf < 4; ++nf) {
            const int col = n0 + wn + nf * 16 + cl;
            const float bv = bias[col];
#pragma unroll
            for (int r = 0; r < 4; ++r) {
                const int row = m0 + wm + mf * 16 + kg * 4 + r;
                float v = acc[mf][nf][r] + bv;
                if (col < scaleN) v *= scaleV;
                if (OUTF32)
                    ((float*)Cout)[(size_t)row * N + col] = v;
                else
                    ((unsigned short*)Cout)[(size_t)row * N + col] = f2bf(v);
            }
        }
    }
}

// ---------------- flash attention v7: shared KV tile in LDS, 4 waves/block ----------------
// Same as v6 (R6) but with an EXPLICIT s_waitcnt vmcnt(0) lgkmcnt(0) before every
// __syncthreads in the tile loop. R6 raced intermittently (post-timing absmax 3.0e-2):
// the compiler is not guaranteed to emit the full counter drain before s_barrier, so a
// wave could signal the barrier while its global_load_lds writes (or ds_reads of the
// buffer about to be overwritten) were still in flight. The explicit drain makes the
// producer-release/consumer-complete ordering unconditional; cost ~0 (barrier waits on
// the slowest wave anyway).
__global__ __launch_bounds__(256) void attn_fwd6(const unsigned short* __restrict__ qkv,
                                                 const unsigned short* __restrict__ vt,
                                                 unsigned short* __restrict__ aout) {
    constexpr int S = 2048, RS = 3072;
    __shared__ __align__(16) unsigned short Klds[2][64 * 64];
    __shared__ __align__(16) unsigned short Vlds[2][64 * 64];
    const int tid = threadIdx.x;
    const int l = tid & 63, w = tid >> 6;
    const int q31 = l & 31, hi = l >> 5;
    const int bh = blockIdx.y, b = bh >> 4, h = bh & 15;
    const int strip = (int)gridDim.x - 1 - (int)blockIdx.x;  // heavy blocks first
    const int q0 = strip * 128 + w * 32;
    const int q = q0 + q31;
    const unsigned short* Qp = qkv + (size_t)b * S * RS + h * 64;
    const unsigned short* Kp = Qp + 1024;
    const unsigned short* Vtp = vt + (size_t)bh * 64 * S;

    bf16x8 qf[4];
#pragma unroll
    for (int kf = 0; kf < 4; ++kf)
        qf[kf] = *(const bf16x8*)&Qp[(size_t)q * RS + kf * 16 + hi * 8];

    float m = -1e30f, lsum = 0.f;
    f32x16 oacc[2] = {};

    // staging map: wave w stages K rows [w*16,w*16+16) and V rows [w*16,w*16+16),
    // 2 instrs each of 8 rows; source pre-swizzled (rule 21): lds[row][c16] =
    // glob[row][c16 ^ (row&7)], srow == row&7 for the staged row.
    const int srow = l >> 3;                    // 0..7 within the 8-row group
    const int sc16 = (l & 7) ^ srow;            // pre-swizzled source col16
    const int swz = q31 & 7;                    // read-side XOR for this lane's rows

    const int Tb = 2 * strip + 2;               // 64-key tiles covering the strip
    const int tlast = (q0 + 31) >> 6;           // last tile this wave computes

#define STAGE(buf, t)                                                                   \
    {                                                                                   \
        const int s0_ = (t) * 64;                                                       \
        _Pragma("unroll")                                                               \
        for (int j = 0; j < 2; ++j) {                                                   \
            const int row = w * 16 + j * 8 + srow;                                      \
            async_copy16(Kp + (size_t)(s0_ + row) * RS + sc16 * 8,                      \
                         &Klds[buf][(w * 16 + j * 8) * 64]);                            \
            async_copy16(Vtp + (size_t)row * S + s0_ + sc16 * 8,                        \
                         &Vlds[buf][(w * 16 + j * 8) * 64]);                            \
        }                                                                               \
    }

    STAGE(0, 0);
    int cur = 0;

    for (int t = 0; t < Tb; ++t) {
        // explicit drain: my staging writes landed, my reads of the other buffer done
        asm volatile("s_waitcnt vmcnt(0) lgkmcnt(0)" ::: "memory");
        __syncthreads();                        // staged tile t ready; prev buf free
        if (t + 1 < Tb) STAGE(cur ^ 1, t + 1);

        if (t <= tlast) {
            const int s0 = t * 64;

            // ---- K frags from swizzled LDS ----
            bf16x8 kb[2][4];
#pragma unroll
            for (int kt = 0; kt < 2; ++kt)
#pragma unroll
                for (int kf = 0; kf < 4; ++kf)
                    kb[kt][kf] = *(const bf16x8*)&Klds[cur][(kt * 32 + q31) * 64 + ((kf * 2 + hi) ^ swz) * 8];

            // ---- T[key][q] = K @ Q^T (swapped) ----
            f32x16 tacc[2] = {};
            __builtin_amdgcn_s_setprio(1);
#pragma unroll
            for (int kt = 0; kt < 2; ++kt)
#pragma unroll
                for (int kf = 0; kf < 4; ++kf)
                    tacc[kt] = mfma32(kb[kt][kf], qf[kf], tacc[kt]);
            __builtin_amdgcn_s_setprio(0);

            // ---- V frags from swizzled LDS ----
            bf16x8 vb[2][4];
#pragma unroll
            for (int df = 0; df < 2; ++df)
#pragma unroll
                for (int ks = 0; ks < 4; ++ks)
                    vb[df][ks] = *(const bf16x8*)&Vlds[cur][(df * 32 + q31) * 64 + ((ks * 2 + hi) ^ swz) * 8];

            // ---- causal mask ----
            const bool partial = (t * 64 + 63 > q0);
            float pv[2][16];
#pragma unroll
            for (int kt = 0; kt < 2; ++kt)
#pragma unroll
                for (int r = 0; r < 16; ++r) {
                    const int key = s0 + kt * 32 + (r & 3) + ((r >> 2) << 3) + hi * 4;
                    float sv = tacc[kt][r];
                    if (partial && key > q) sv = -1e30f;
                    pv[kt][r] = sv;
                }

            // ---- row max ----
            float rx = pv[0][0];
#pragma unroll
            for (int kt = 0; kt < 2; ++kt)
#pragma unroll
                for (int r = 0; r < 16; ++r) rx = fmaxf(rx, pv[kt][r]);
            rx = fmaxf(rx, __shfl_xor(rx, 32, 64));

            // ---- defer-max rescale (THR = 8*log2e) ----
            if (__any(rx - m > 11.5f)) {
                const float mn = fmaxf(m, rx);
                const float alpha = exp2f_fast(m - mn);
                lsum *= alpha;
                m = mn;
#pragma unroll
                for (int r = 0; r < 16; ++r) {
                    const float ar = __shfl(alpha, (r & 3) + ((r >> 2) << 3) + hi * 4, 64);
                    oacc[0][r] *= ar;
                    oacc[1][r] *= ar;
                }
            }

            // ---- exp2 + pack + row sum ----
            unsigned int pk[2][4][2];
            float rsum = 0.f;
#pragma unroll
            for (int kt = 0; kt < 2; ++kt)
#pragma unroll
                for (int g = 0; g < 4; ++g) {
                    const float e0 = exp2f_fast(pv[kt][g * 4 + 0] - m);
                    const float e1 = exp2f_fast(pv[kt][g * 4 + 1] - m);
                    const float e2 = exp2f_fast(pv[kt][g * 4 + 2] - m);
                    const float e3 = exp2f_fast(pv[kt][g * 4 + 3] - m);
                    pk[kt][g][0] = cvtpk(e0, e1);
                    pk[kt][g][1] = cvtpk(e2, e3);
                    rsum += (e0 + e1) + (e2 + e3);
                }
            rsum += __shfl_xor(rsum, 32, 64);
            lsum += rsum;

            // ---- PV: select-based PA assembly (shfl half-swap, verified) ----
#pragma unroll
            for (int ks = 0; ks < 4; ++ks) {
                const int kt = ks >> 1, kslo = ks & 1;
                const unsigned int pkA0 = pk[kt][2 * kslo][0],     pkA1 = pk[kt][2 * kslo][1];
                const unsigned int pkB0 = pk[kt][2 * kslo + 1][0], pkB1 = pk[kt][2 * kslo + 1][1];
                const unsigned int send0 = hi ? pkA0 : pkB0;
                const unsigned int send1 = hi ? pkA1 : pkB1;
                const unsigned int own0  = hi ? pkB0 : pkA0;
                const unsigned int own1  = hi ? pkB1 : pkA1;
                const unsigned int recv0 = (unsigned int)__shfl_xor((int)send0, 32, 64);
                const unsigned int recv1 = (unsigned int)__shfl_xor((int)send1, 32, 64);
                u32x4 u;
                u[0] = hi ? recv0 : own0;
                u[1] = hi ? recv1 : own1;
                u[2] = hi ? own0 : recv0;
                u[3] = hi ? own1 : recv1;
                const bf16x8 pa = __builtin_bit_cast(bf16x8, u);
                __builtin_amdgcn_s_setprio(1);
                oacc[0] = mfma32(pa, vb[0][ks], oacc[0]);
                oacc[1] = mfma32(pa, vb[1][ks], oacc[1]);
                __builtin_amdgcn_s_setprio(0);
            }
        }
        cur ^= 1;
    }
#undef STAGE

    // ---- epilogue: O /= l ----
    const float linv = 1.f / lsum;
#pragma unroll
    for (int r = 0; r < 16; ++r) {
        const int qrow = (r & 3) + ((r >> 2) << 3) + hi * 4;
        const float lr = __shfl(linv, qrow, 64);
        const int row = q0 + qrow;
        aout[(size_t)(b * S + row) * 1024 + h * 64 + q31]      = f2bf(oacc[0][r] * lr);
        aout[(size_t)(b * S + row) * 1024 + h * 64 + 32 + q31] = f2bf(oacc[1][r] * lr);
    }
}

extern "C" void kernel_launch(void* const* d_in, const int* in_sizes, int n_in,
                              void* d_out, int out_size, void* d_ws, size_t ws_size,
                              hipStream_t stream) {
    (void)in_sizes; (void)n_in; (void)out_size; (void)ws_size;
    const float* hs    = (const float*)d_in[0];  // [2,2048,1024]
    const float* wqkv  = (const float*)d_in[1];  // [1024,3072]
    const float* bqkv  = (const float*)d_in[2];  // [3072]
    const float* wproj = (const float*)d_in[3];  // [1024,1024]
    const float* bproj = (const float*)d_in[4];  // [1024]
    float* out = (float*)d_out;                  // [2,2048,1024] f32

    unsigned short* Xb  = (unsigned short*)d_ws;                 // 4096*1024 (reused as Vt)
    unsigned short* Wqt = Xb  + (size_t)4096 * 1024;             // 3072*1024
    unsigned short* Wpt = Wqt + (size_t)3072 * 1024;             // 1024*1024
    unsigned short* QKV = Wpt + (size_t)1024 * 1024;             // 4096*3072
    unsigned short* AO  = QKV + (size_t)4096 * 3072;             // 4096*1024
    unsigned short* Vt  = Xb;  // X dead after QKV GEMM; Vt = [32 bh][64 d][2048 s]

    const float qscale = 0.125f * 1.4426950408889634f;  // fold softmax scale + log2e into Q

    convert_bf16<<<4096, 256, 0, stream>>>(hs, Xb, 4096 * 1024);
    transpose_convert<<<dim3(3072 / 32, 1024 / 32), 256, 0, stream>>>(wqkv, Wqt, 1024, 3072);
    transpose_convert<<<dim3(1024 / 32, 1024 / 32), 256, 0, stream>>>(wproj, Wpt, 1024, 1024);

    gemm_bt<0><<<dim3(32, 24), 256, 0, stream>>>(Xb, Wqt, bqkv, (void*)QKV, 4096, 3072, 1024,
                                                 1024, qscale);
    transpose_v<<<dim3(64, 2, 32), 256, 0, stream>>>(QKV, Vt);
    attn_fwd6<<<dim3(16, 32), 256, 0, stream>>>(QKV, Vt, AO);
    gemm_bt<1><<<dim3(32, 8), 256, 0, stream>>>(AO, Wpt, bproj, (void*)out, 4096, 1024, 1024,
                                                0, 1.0f);
}

// Round 9
// 138.962 us; speedup vs baseline: 2.5897x; 1.1551x over previous
//
#include <hip/hip_runtime.h>
#include <cstdint>

typedef __attribute__((ext_vector_type(8))) __bf16 bf16x8;
typedef __attribute__((ext_vector_type(4))) float f32x4;
typedef __attribute__((ext_vector_type(16))) float f32x16;
typedef __attribute__((ext_vector_type(4))) unsigned int u32x4;

#define DEV __device__ __forceinline__

DEV unsigned short f2bf(float f) {
    unsigned int u = __builtin_bit_cast(unsigned int, f);
    u += 0x7fffu + ((u >> 16) & 1u);   // RNE
    return (unsigned short)(u >> 16);
}

DEV void async_copy16(const void* g, void* l) {
    __builtin_amdgcn_global_load_lds(
        (const __attribute__((address_space(1))) unsigned int*)g,
        (__attribute__((address_space(3))) unsigned int*)l, 16, 0, 0);
}

DEV f32x4 mfma16(bf16x8 a, bf16x8 b, f32x4 c) {
    return __builtin_amdgcn_mfma_f32_16x16x32_bf16(a, b, c, 0, 0, 0);
}
DEV f32x16 mfma32(bf16x8 a, bf16x8 b, f32x16 c) {
    return __builtin_amdgcn_mfma_f32_32x32x16_bf16(a, b, c, 0, 0, 0);
}
DEV unsigned int cvtpk(float lo, float hi) {
    unsigned int d;
    asm("v_cvt_pk_bf16_f32 %0, %1, %2" : "=v"(d) : "v"(lo), "v"(hi));
    return d;
}
DEV float exp2f_fast(float x) { return __builtin_amdgcn_exp2f(x); }

// ---------------- f32 -> bf16 convert (vectorized) ----------------
__global__ __launch_bounds__(256) void convert_bf16(const float* __restrict__ in,
                                                    unsigned short* __restrict__ outp, int n) {
    int i = (blockIdx.x * 256 + threadIdx.x) * 4;
    if (i >= n) return;
    float4 v = *(const float4*)&in[i];
    ushort4 o;
    o.x = f2bf(v.x); o.y = f2bf(v.y); o.z = f2bf(v.z); o.w = f2bf(v.w);
    *(ushort4*)&outp[i] = o;
}

// ---------------- W[K][N] f32 -> Wt[N][K] bf16 ----------------
__global__ __launch_bounds__(256) void transpose_convert(const float* __restrict__ W,
                                                         unsigned short* __restrict__ Wt,
                                                         int K, int N) {
    __shared__ float tile[32][33];
    int n0 = blockIdx.x * 32, k0 = blockIdx.y * 32;
    int tx = threadIdx.x & 31, ty = threadIdx.x >> 5;  // ty 0..7
#pragma unroll
    for (int i = 0; i < 32; i += 8)
        tile[ty + i][tx] = W[(size_t)(k0 + ty + i) * N + n0 + tx];
    __syncthreads();
#pragma unroll
    for (int i = 0; i < 32; i += 8)
        Wt[(size_t)(n0 + ty + i) * K + k0 + tx] = f2bf(tile[tx][ty + i]);
}

// ---------------- V part of QKV -> Vt[b][h][d][s] (bf16 -> bf16) ----------------
__global__ __launch_bounds__(256) void transpose_v(const unsigned short* __restrict__ qkv,
                                                   unsigned short* __restrict__ vt) {
    constexpr int S = 2048, RS = 3072;
    __shared__ unsigned short tile[32][33];
    const int s0 = blockIdx.x * 32, d0 = blockIdx.y * 32, bh = blockIdx.z;
    const int b = bh >> 4, h = bh & 15;
    const int tx = threadIdx.x & 31, ty = threadIdx.x >> 5;  // ty 0..7
#pragma unroll
    for (int i = 0; i < 32; i += 8)
        tile[ty + i][tx] = qkv[(size_t)(b * S + s0 + ty + i) * RS + 2048 + h * 64 + d0 + tx];
    __syncthreads();
#pragma unroll
    for (int i = 0; i < 32; i += 8)
        vt[(size_t)(bh * 64 + d0 + ty + i) * S + s0 + tx] = tile[tx][ty + i];
}

// ---------------- GEMM v2: C = A @ Bt^T + bias. BK=64, swizzled LDS ----------------
// 128x128 tile, BK=64, 4 waves (2x2 of 64x64). LDS [128][64] per matrix, staged via
// global_load_lds w/ pre-swizzled source chunk (c16 ^= row&7, R7-proven pattern) ->
// frag ds_read_b128 is 2-way (free) instead of the m98-class 8-way conflict.
// Half the barriers of BK=32.
template <int OUTF32>
__global__ __launch_bounds__(256) void gemm_bt(const unsigned short* __restrict__ A,
                                               const unsigned short* __restrict__ Bt,
                                               const float* __restrict__ bias,
                                               void* __restrict__ Cout,
                                               int M, int N, int K,
                                               int scaleN, float scaleV) {
    __shared__ __align__(16) unsigned short Asl[128][64];
    __shared__ __align__(16) unsigned short Bsl[128][64];
    const int tid = threadIdx.x;
    const int lane = tid & 63, w = tid >> 6;
    const int cl = lane & 15, kg = lane >> 4;
    const int m0 = blockIdx.x * 128, n0 = blockIdx.y * 128;
    const int wm = (w >> 1) * 64, wn = (w & 1) * 64;

    f32x4 acc[4][4] = {};

    // staging map: wave w stages rows [w*32, w*32+32), 4 chunks of 8 rows per matrix.
    // lane l -> row offset l>>3, source col16 (l&7)^(l>>3) (pre-swizzle, rule 21).
    const int rs8 = lane >> 3;
    const int sc16 = (lane & 7) ^ rs8;
    const int swz = cl & 7;                     // read-side XOR (row&7 for frag rows)

    for (int k0 = 0; k0 < K; k0 += 64) {
#pragma unroll
        for (int j = 0; j < 4; ++j) {
            const int row = w * 32 + j * 8;
            async_copy16(A + (size_t)(m0 + row + rs8) * K + k0 + sc16 * 8, &Asl[row][0]);
            async_copy16(Bt + (size_t)(n0 + row + rs8) * K + k0 + sc16 * 8, &Bsl[row][0]);
        }
        asm volatile("s_waitcnt vmcnt(0)" ::: "memory");
        __syncthreads();

#pragma unroll
        for (int kk = 0; kk < 2; ++kk) {
            bf16x8 af[4], bfv[4];
#pragma unroll
            for (int mf = 0; mf < 4; ++mf)
                af[mf] = *(const bf16x8*)&Asl[wm + mf * 16 + cl][(((kk << 2) + kg) ^ swz) * 8];
#pragma unroll
            for (int nf = 0; nf < 4; ++nf)
                bfv[nf] = *(const bf16x8*)&Bsl[wn + nf * 16 + cl][(((kk << 2) + kg) ^ swz) * 8];
#pragma unroll
            for (int mf = 0; mf < 4; ++mf)
#pragma unroll
                for (int nf = 0; nf < 4; ++nf)
                    acc[mf][nf] = mfma16(af[mf], bfv[nf], acc[mf][nf]);
        }
        __syncthreads();
    }

#pragma unroll
    for (int mf = 0; mf < 4; ++mf) {
#pragma unroll
        for (int nf = 0; nf < 4; ++nf) {
            const int col = n0 + wn + nf * 16 + cl;
            const float bv = bias[col];
#pragma unroll
            for (int r = 0; r < 4; ++r) {
                const int row = m0 + wm + mf * 16 + kg * 4 + r;
                float v = acc[mf][nf][r] + bv;
                if (col < scaleN) v *= scaleV;
                if (OUTF32)
                    ((float*)Cout)[(size_t)row * N + col] = v;
                else
                    ((unsigned short*)Cout)[(size_t)row * N + col] = f2bf(v);
            }
        }
    }
}

// ---------------- flash attention v8: shared KV LDS + complementary strip pairing ----
// 512 blocks, 4 waves each. Block cost ~ 2*strip+2 tile-units; blocks i and i+256 land
// on the SAME CU (same XCD i%8, same slot), so we pair complementary strips: position
// c in half 0 -> strip 15-(c&7), position c in half 1 -> strip (c&7). Every CU's two
// blocks sum to 34 tile-units -> uniform makespan (was 48 with heavy-first).
// Causal masking only on the (wave-uniform) partial tiles.
__global__ __launch_bounds__(256) void attn_fwd8(const unsigned short* __restrict__ qkv,
                                                 const unsigned short* __restrict__ vt,
                                                 unsigned short* __restrict__ aout) {
    constexpr int S = 2048, RS = 3072;
    __shared__ __align__(16) unsigned short Klds[2][64 * 64];
    __shared__ __align__(16) unsigned short Vlds[2][64 * 64];
    const int tid = threadIdx.x;
    const int l = tid & 63, w = tid >> 6;
    const int q31 = l & 31, hi = l >> 5;

    // complementary pairing: id 0..511, half = id>>8, c = id&255
    const int id = (int)(blockIdx.y * gridDim.x + blockIdx.x);
    const int half = id >> 8, c = id & 255;
    const int j = c & 7, bh = c >> 3;
    const int strip = half ? j : 15 - j;

    const int b = bh >> 4, h = bh & 15;
    const int q0 = strip * 128 + w * 32;
    const int q = q0 + q31;
    const unsigned short* Qp = qkv + (size_t)b * S * RS + h * 64;
    const unsigned short* Kp = Qp + 1024;
    const unsigned short* Vtp = vt + (size_t)bh * 64 * S;

    bf16x8 qf[4];
#pragma unroll
    for (int kf = 0; kf < 4; ++kf)
        qf[kf] = *(const bf16x8*)&Qp[(size_t)q * RS + kf * 16 + hi * 8];

    float m = -1e30f, lsum = 0.f;
    f32x16 oacc[2] = {};

    const int srow = l >> 3;                    // 0..7 within the 8-row group
    const int sc16 = (l & 7) ^ srow;            // pre-swizzled source col16
    const int swz = q31 & 7;                    // read-side XOR for this lane's rows

    const int Tb = 2 * strip + 2;               // 64-key tiles covering the strip
    const int tlast = (q0 + 31) >> 6;           // last tile this wave computes

#define STAGE(buf, t)                                                                   \
    {                                                                                   \
        const int s0_ = (t) * 64;                                                       \
        _Pragma("unroll")                                                               \
        for (int jj = 0; jj < 2; ++jj) {                                                \
            const int row = w * 16 + jj * 8 + srow;                                     \
            async_copy16(Kp + (size_t)(s0_ + row) * RS + sc16 * 8,                      \
                         &Klds[buf][(w * 16 + jj * 8) * 64]);                           \
            async_copy16(Vtp + (size_t)row * S + s0_ + sc16 * 8,                        \
                         &Vlds[buf][(w * 16 + jj * 8) * 64]);                           \
        }                                                                               \
    }

    STAGE(0, 0);
    int cur = 0;

    for (int t = 0; t < Tb; ++t) {
        // explicit drain (R7): staging writes landed, prev-buffer reads complete
        asm volatile("s_waitcnt vmcnt(0) lgkmcnt(0)" ::: "memory");
        __syncthreads();                        // staged tile t ready; prev buf free
        if (t + 1 < Tb) STAGE(cur ^ 1, t + 1);

        if (t <= tlast) {
            const int s0 = t * 64;

            // ---- K frags from swizzled LDS ----
            bf16x8 kb[2][4];
#pragma unroll
            for (int kt = 0; kt < 2; ++kt)
#pragma unroll
                for (int kf = 0; kf < 4; ++kf)
                    kb[kt][kf] = *(const bf16x8*)&Klds[cur][(kt * 32 + q31) * 64 + ((kf * 2 + hi) ^ swz) * 8];

            // ---- T[key][q] = K @ Q^T (swapped) ----
            f32x16 tacc[2] = {};
            __builtin_amdgcn_s_setprio(1);
#pragma unroll
            for (int kt = 0; kt < 2; ++kt)
#pragma unroll
                for (int kf = 0; kf < 4; ++kf)
                    tacc[kt] = mfma32(kb[kt][kf], qf[kf], tacc[kt]);
            __builtin_amdgcn_s_setprio(0);

            // ---- V frags from swizzled LDS ----
            bf16x8 vb[2][4];
#pragma unroll
            for (int df = 0; df < 2; ++df)
#pragma unroll
                for (int ks = 0; ks < 4; ++ks)
                    vb[df][ks] = *(const bf16x8*)&Vlds[cur][(df * 32 + q31) * 64 + ((ks * 2 + hi) ^ swz) * 8];

            // ---- causal mask: only the 1-2 partial tiles per wave pay for it ----
            const bool partial = (s0 + 63 > q0);
            float pv[2][16];
            if (partial) {
#pragma unroll
                for (int kt = 0; kt < 2; ++kt)
#pragma unroll
                    for (int r = 0; r < 16; ++r) {
                        const int key = s0 + kt * 32 + (r & 3) + ((r >> 2) << 3) + hi * 4;
                        float sv = tacc[kt][r];
                        if (key > q) sv = -1e30f;
                        pv[kt][r] = sv;
                    }
            } else {
#pragma unroll
                for (int kt = 0; kt < 2; ++kt)
#pragma unroll
                    for (int r = 0; r < 16; ++r) pv[kt][r] = tacc[kt][r];
            }

            // ---- row max ----
            float rx = pv[0][0];
#pragma unroll
            for (int kt = 0; kt < 2; ++kt)
#pragma unroll
                for (int r = 0; r < 16; ++r) rx = fmaxf(rx, pv[kt][r]);
            rx = fmaxf(rx, __shfl_xor(rx, 32, 64));

            // ---- defer-max rescale (THR = 8*log2e) ----
            if (__any(rx - m > 11.5f)) {
                const float mn = fmaxf(m, rx);
                const float alpha = exp2f_fast(m - mn);
                lsum *= alpha;
                m = mn;
#pragma unroll
                for (int r = 0; r < 16; ++r) {
                    const float ar = __shfl(alpha, (r & 3) + ((r >> 2) << 3) + hi * 4, 64);
                    oacc[0][r] *= ar;
                    oacc[1][r] *= ar;
                }
            }

            // ---- exp2 + pack + row sum ----
            unsigned int pk[2][4][2];
            float rsum = 0.f;
#pragma unroll
            for (int kt = 0; kt < 2; ++kt)
#pragma unroll
                for (int g = 0; g < 4; ++g) {
                    const float e0 = exp2f_fast(pv[kt][g * 4 + 0] - m);
                    const float e1 = exp2f_fast(pv[kt][g * 4 + 1] - m);
                    const float e2 = exp2f_fast(pv[kt][g * 4 + 2] - m);
                    const float e3 = exp2f_fast(pv[kt][g * 4 + 3] - m);
                    pk[kt][g][0] = cvtpk(e0, e1);
                    pk[kt][g][1] = cvtpk(e2, e3);
                    rsum += (e0 + e1) + (e2 + e3);
                }
            rsum += __shfl_xor(rsum, 32, 64);
            lsum += rsum;

            // ---- PV: select-based PA assembly (shfl half-swap, verified) ----
#pragma unroll
            for (int ks = 0; ks < 4; ++ks) {
                const int kt = ks >> 1, kslo = ks & 1;
                const unsigned int pkA0 = pk[kt][2 * kslo][0],     pkA1 = pk[kt][2 * kslo][1];
                const unsigned int pkB0 = pk[kt][2 * kslo + 1][0], pkB1 = pk[kt][2 * kslo + 1][1];
                const unsigned int send0 = hi ? pkA0 : pkB0;
                const unsigned int send1 = hi ? pkA1 : pkB1;
                const unsigned int own0  = hi ? pkB0 : pkA0;
                const unsigned int own1  = hi ? pkB1 : pkA1;
                const unsigned int recv0 = (unsigned int)__shfl_xor((int)send0, 32, 64);
                const unsigned int recv1 = (unsigned int)__shfl_xor((int)send1, 32, 64);
                u32x4 u;
                u[0] = hi ? recv0 : own0;
                u[1] = hi ? recv1 : own1;
                u[2] = hi ? own0 : recv0;
                u[3] = hi ? own1 : recv1;
                const bf16x8 pa = __builtin_bit_cast(bf16x8, u);
                __builtin_amdgcn_s_setprio(1);
                oacc[0] = mfma32(pa, vb[0][ks], oacc[0]);
                oacc[1] = mfma32(pa, vb[1][ks], oacc[1]);
                __builtin_amdgcn_s_setprio(0);
            }
        }
        cur ^= 1;
    }
#undef STAGE

    // ---- epilogue: O /= l ----
    const float linv = 1.f / lsum;
#pragma unroll
    for (int r = 0; r < 16; ++r) {
        const int qrow = (r & 3) + ((r >> 2) << 3) + hi * 4;
        const float lr = __shfl(linv, qrow, 64);
        const int row = q0 + qrow;
        aout[(size_t)(b * S + row) * 1024 + h * 64 + q31]      = f2bf(oacc[0][r] * lr);
        aout[(size_t)(b * S + row) * 1024 + h * 64 + 32 + q31] = f2bf(oacc[1][r] * lr);
    }
}

extern "C" void kernel_launch(void* const* d_in, const int* in_sizes, int n_in,
                              void* d_out, int out_size, void* d_ws, size_t ws_size,
                              hipStream_t stream) {
    (void)in_sizes; (void)n_in; (void)out_size; (void)ws_size;
    const float* hs    = (const float*)d_in[0];  // [2,2048,1024]
    const float* wqkv  = (const float*)d_in[1];  // [1024,3072]
    const float* bqkv  = (const float*)d_in[2];  // [3072]
    const float* wproj = (const float*)d_in[3];  // [1024,1024]
    const float* bproj = (const float*)d_in[4];  // [1024]
    float* out = (float*)d_out;                  // [2,2048,1024] f32

    unsigned short* Xb  = (unsigned short*)d_ws;                 // 4096*1024 (reused as Vt)
    unsigned short* Wqt = Xb  + (size_t)4096 * 1024;             // 3072*1024
    unsigned short* Wpt = Wqt + (size_t)3072 * 1024;             // 1024*1024
    unsigned short* QKV = Wpt + (size_t)1024 * 1024;             // 4096*3072
    unsigned short* AO  = QKV + (size_t)4096 * 3072;             // 4096*1024
    unsigned short* Vt  = Xb;  // X dead after QKV GEMM; Vt = [32 bh][64 d][2048 s]

    const float qscale = 0.125f * 1.4426950408889634f;  // fold softmax scale + log2e into Q

    convert_bf16<<<4096, 256, 0, stream>>>(hs, Xb, 4096 * 1024);
    transpose_convert<<<dim3(3072 / 32, 1024 / 32), 256, 0, stream>>>(wqkv, Wqt, 1024, 3072);
    transpose_convert<<<dim3(1024 / 32, 1024 / 32), 256, 0, stream>>>(wproj, Wpt, 1024, 1024);

    gemm_bt<0><<<dim3(32, 24), 256, 0, stream>>>(Xb, Wqt, bqkv, (void*)QKV, 4096, 3072, 1024,
                                                 1024, qscale);
    transpose_v<<<dim3(64, 2, 32), 256, 0, stream>>>(QKV, Vt);
    attn_fwd8<<<dim3(16, 32), 256, 0, stream>>>(QKV, Vt, AO);
    gemm_bt<1><<<dim3(32, 8), 256, 0, stream>>>(AO, Wpt, bproj, (void*)out, 4096, 1024, 1024,
                                                0, 1.0f);
}

// Round 10
// 133.276 us; speedup vs baseline: 2.7002x; 1.0427x over previous
//
#include <hip/hip_runtime.h>
#include <cstdint>

typedef __attribute__((ext_vector_type(8))) __bf16 bf16x8;
typedef __attribute__((ext_vector_type(4))) float f32x4;
typedef __attribute__((ext_vector_type(16))) float f32x16;
typedef __attribute__((ext_vector_type(4))) unsigned int u32x4;

#define DEV __device__ __forceinline__

DEV unsigned short f2bf(float f) {
    unsigned int u = __builtin_bit_cast(unsigned int, f);
    u += 0x7fffu + ((u >> 16) & 1u);   // RNE
    return (unsigned short)(u >> 16);
}

DEV void async_copy16(const void* g, void* l) {
    __builtin_amdgcn_global_load_lds(
        (const __attribute__((address_space(1))) unsigned int*)g,
        (__attribute__((address_space(3))) unsigned int*)l, 16, 0, 0);
}

DEV f32x4 mfma16(bf16x8 a, bf16x8 b, f32x4 c) {
    return __builtin_amdgcn_mfma_f32_16x16x32_bf16(a, b, c, 0, 0, 0);
}
DEV f32x16 mfma32(bf16x8 a, bf16x8 b, f32x16 c) {
    return __builtin_amdgcn_mfma_f32_32x32x16_bf16(a, b, c, 0, 0, 0);
}
DEV unsigned int cvtpk(float lo, float hi) {
    unsigned int d;
    asm("v_cvt_pk_bf16_f32 %0, %1, %2" : "=v"(d) : "v"(lo), "v"(hi));
    return d;
}
DEV float exp2f_fast(float x) { return __builtin_amdgcn_exp2f(x); }

// ---------------- f32 -> bf16 convert (vectorized) ----------------
__global__ __launch_bounds__(256) void convert_bf16(const float* __restrict__ in,
                                                    unsigned short* __restrict__ outp, int n) {
    int i = (blockIdx.x * 256 + threadIdx.x) * 4;
    if (i >= n) return;
    float4 v = *(const float4*)&in[i];
    ushort4 o;
    o.x = f2bf(v.x); o.y = f2bf(v.y); o.z = f2bf(v.z); o.w = f2bf(v.w);
    *(ushort4*)&outp[i] = o;
}

// ---------------- W[K][N] f32 -> Wt[N][K] bf16 ----------------
__global__ __launch_bounds__(256) void transpose_convert(const float* __restrict__ W,
                                                         unsigned short* __restrict__ Wt,
                                                         int K, int N) {
    __shared__ float tile[32][33];
    int n0 = blockIdx.x * 32, k0 = blockIdx.y * 32;
    int tx = threadIdx.x & 31, ty = threadIdx.x >> 5;  // ty 0..7
#pragma unroll
    for (int i = 0; i < 32; i += 8)
        tile[ty + i][tx] = W[(size_t)(k0 + ty + i) * N + n0 + tx];
    __syncthreads();
#pragma unroll
    for (int i = 0; i < 32; i += 8)
        Wt[(size_t)(n0 + ty + i) * K + k0 + tx] = f2bf(tile[tx][ty + i]);
}

// ---------------- V part of QKV -> Vt[b][h][d][s] (bf16 -> bf16) ----------------
__global__ __launch_bounds__(256) void transpose_v(const unsigned short* __restrict__ qkv,
                                                   unsigned short* __restrict__ vt) {
    constexpr int S = 2048, RS = 3072;
    __shared__ unsigned short tile[32][33];
    const int s0 = blockIdx.x * 32, d0 = blockIdx.y * 32, bh = blockIdx.z;
    const int b = bh >> 4, h = bh & 15;
    const int tx = threadIdx.x & 31, ty = threadIdx.x >> 5;  // ty 0..7
#pragma unroll
    for (int i = 0; i < 32; i += 8)
        tile[ty + i][tx] = qkv[(size_t)(b * S + s0 + ty + i) * RS + 2048 + h * 64 + d0 + tx];
    __syncthreads();
#pragma unroll
    for (int i = 0; i < 32; i += 8)
        vt[(size_t)(bh * 64 + d0 + ty + i) * S + s0 + tx] = tile[tx][ty + i];
}

// ---------------- GEMM v3: double-buffered BK=32, attn-template schedule ----------------
// 128x128 tile, 4 waves (2x2 of 64x64). LDS [2][128][32] per matrix (32 KB total).
// Schedule = the R7-proven attn template: STAGE(0); loop { drain; bar; STAGE(t+1,buf^1);
// compute(buf); } -- staging latency hides under MFMA + co-resident blocks, one barrier
// per K-step. Swizzle: chunk' = c16 ^ ((row>>1)&3) -> frag ds_read_b128 is 2-way (free).
// XCD-chunked block swizzle (nwg % 8 == 0 for both call sites).
template <int OUTF32>
__global__ __launch_bounds__(256) void gemm_bt(const unsigned short* __restrict__ A,
                                               const unsigned short* __restrict__ Bt,
                                               const float* __restrict__ bias,
                                               void* __restrict__ Cout,
                                               int M, int N, int K,
                                               int scaleN, float scaleV) {
    __shared__ __align__(16) unsigned short Asl[2][128][32];
    __shared__ __align__(16) unsigned short Bsl[2][128][32];
    const int tid = threadIdx.x;
    const int lane = tid & 63, w = tid >> 6;
    const int cl = lane & 15, kg = lane >> 4;

    // XCD-chunked swizzle: each XCD gets nwg/8 consecutive tiles (L2 panel reuse)
    const int nwg = (int)(gridDim.x * gridDim.y);
    const int flat = (int)(blockIdx.y * gridDim.x + blockIdx.x);
    const int swzb = (flat & 7) * (nwg >> 3) + (flat >> 3);
    const int m0 = (swzb % (int)gridDim.x) * 128;
    const int n0 = (swzb / (int)gridDim.x) * 128;

    const int wm = (w >> 1) * 64, wn = (w & 1) * 64;

    f32x4 acc[4][4] = {};

    // staging map: wave w stages rows [w*32, w*32+32) of A and B, 2 instrs each of
    // 16 rows. lane l -> row l>>2, source chunk (l&3) ^ ((l>>3)&3)  [= c ^ ((row>>1)&3)].
    const int srow16 = lane >> 2;
    const int sc4 = (lane & 3) ^ ((lane >> 3) & 3);
    const int rdswz = (cl >> 1) & 3;            // read-side XOR: (row>>1)&3 == (cl>>1)&3

    const int T = K >> 5;
#define GSTAGE(buf, t)                                                                    \
    {                                                                                     \
        const int k0_ = (t) << 5;                                                         \
        _Pragma("unroll")                                                                 \
        for (int j = 0; j < 2; ++j) {                                                     \
            const int row = w * 32 + j * 16;                                              \
            async_copy16(A + (size_t)(m0 + row + srow16) * K + k0_ + sc4 * 8,             \
                         &Asl[buf][row][0]);                                              \
            async_copy16(Bt + (size_t)(n0 + row + srow16) * K + k0_ + sc4 * 8,            \
                         &Bsl[buf][row][0]);                                              \
        }                                                                                 \
    }

    GSTAGE(0, 0);
    int cur = 0;

    for (int t = 0; t < T; ++t) {
        asm volatile("s_waitcnt vmcnt(0) lgkmcnt(0)" ::: "memory");
        __syncthreads();                        // buf staged; prev buf reads complete
        if (t + 1 < T) GSTAGE(cur ^ 1, t + 1);

        bf16x8 af[4], bfv[4];
#pragma unroll
        for (int mf = 0; mf < 4; ++mf)
            af[mf] = *(const bf16x8*)&Asl[cur][wm + mf * 16 + cl][(kg ^ rdswz) * 8];
#pragma unroll
        for (int nf = 0; nf < 4; ++nf)
            bfv[nf] = *(const bf16x8*)&Bsl[cur][wn + nf * 16 + cl][(kg ^ rdswz) * 8];
        __builtin_amdgcn_s_setprio(1);
#pragma unroll
        for (int mf = 0; mf < 4; ++mf)
#pragma unroll
            for (int nf = 0; nf < 4; ++nf)
                acc[mf][nf] = mfma16(af[mf], bfv[nf], acc[mf][nf]);
        __builtin_amdgcn_s_setprio(0);
        cur ^= 1;
    }
#undef GSTAGE

#pragma unroll
    for (int mf = 0; mf < 4; ++mf) {
#pragma unroll
        for (int nf = 0; nf < 4; ++nf) {
            const int col = n0 + wn + nf * 16 + cl;
            const float bv = bias[col];
#pragma unroll
            for (int r = 0; r < 4; ++r) {
                const int row = m0 + wm + mf * 16 + kg * 4 + r;
                float v = acc[mf][nf][r] + bv;
                if (col < scaleN) v *= scaleV;
                if (OUTF32)
                    ((float*)Cout)[(size_t)row * N + col] = v;
                else
                    ((unsigned short*)Cout)[(size_t)row * N + col] = f2bf(v);
            }
        }
    }
}

// ---------------- flash attention v8 (unchanged from R8) ----------------
__global__ __launch_bounds__(256) void attn_fwd8(const unsigned short* __restrict__ qkv,
                                                 const unsigned short* __restrict__ vt,
                                                 unsigned short* __restrict__ aout) {
    constexpr int S = 2048, RS = 3072;
    __shared__ __align__(16) unsigned short Klds[2][64 * 64];
    __shared__ __align__(16) unsigned short Vlds[2][64 * 64];
    const int tid = threadIdx.x;
    const int l = tid & 63, w = tid >> 6;
    const int q31 = l & 31, hi = l >> 5;

    // complementary pairing: id 0..511, half = id>>8, c = id&255
    const int id = (int)(blockIdx.y * gridDim.x + blockIdx.x);
    const int half = id >> 8, c = id & 255;
    const int j = c & 7, bh = c >> 3;
    const int strip = half ? j : 15 - j;

    const int b = bh >> 4, h = bh & 15;
    const int q0 = strip * 128 + w * 32;
    const int q = q0 + q31;
    const unsigned short* Qp = qkv + (size_t)b * S * RS + h * 64;
    const unsigned short* Kp = Qp + 1024;
    const unsigned short* Vtp = vt + (size_t)bh * 64 * S;

    bf16x8 qf[4];
#pragma unroll
    for (int kf = 0; kf < 4; ++kf)
        qf[kf] = *(const bf16x8*)&Qp[(size_t)q * RS + kf * 16 + hi * 8];

    float m = -1e30f, lsum = 0.f;
    f32x16 oacc[2] = {};

    const int srow = l >> 3;                    // 0..7 within the 8-row group
    const int sc16 = (l & 7) ^ srow;            // pre-swizzled source col16
    const int swz = q31 & 7;                    // read-side XOR for this lane's rows

    const int Tb = 2 * strip + 2;               // 64-key tiles covering the strip
    const int tlast = (q0 + 31) >> 6;           // last tile this wave computes

#define STAGE(buf, t)                                                                   \
    {                                                                                   \
        const int s0_ = (t) * 64;                                                       \
        _Pragma("unroll")                                                               \
        for (int jj = 0; jj < 2; ++jj) {                                                \
            const int row = w * 16 + jj * 8 + srow;                                     \
            async_copy16(Kp + (size_t)(s0_ + row) * RS + sc16 * 8,                      \
                         &Klds[buf][(w * 16 + jj * 8) * 64]);                           \
            async_copy16(Vtp + (size_t)row * S + s0_ + sc16 * 8,                        \
                         &Vlds[buf][(w * 16 + jj * 8) * 64]);                           \
        }                                                                               \
    }

    STAGE(0, 0);
    int cur = 0;

    for (int t = 0; t < Tb; ++t) {
        // explicit drain (R7): staging writes landed, prev-buffer reads complete
        asm volatile("s_waitcnt vmcnt(0) lgkmcnt(0)" ::: "memory");
        __syncthreads();                        // staged tile t ready; prev buf free
        if (t + 1 < Tb) STAGE(cur ^ 1, t + 1);

        if (t <= tlast) {
            const int s0 = t * 64;

            // ---- K frags from swizzled LDS ----
            bf16x8 kb[2][4];
#pragma unroll
            for (int kt = 0; kt < 2; ++kt)
#pragma unroll
                for (int kf = 0; kf < 4; ++kf)
                    kb[kt][kf] = *(const bf16x8*)&Klds[cur][(kt * 32 + q31) * 64 + ((kf * 2 + hi) ^ swz) * 8];

            // ---- T[key][q] = K @ Q^T (swapped) ----
            f32x16 tacc[2] = {};
            __builtin_amdgcn_s_setprio(1);
#pragma unroll
            for (int kt = 0; kt < 2; ++kt)
#pragma unroll
                for (int kf = 0; kf < 4; ++kf)
                    tacc[kt] = mfma32(kb[kt][kf], qf[kf], tacc[kt]);
            __builtin_amdgcn_s_setprio(0);

            // ---- V frags from swizzled LDS ----
            bf16x8 vb[2][4];
#pragma unroll
            for (int df = 0; df < 2; ++df)
#pragma unroll
                for (int ks = 0; ks < 4; ++ks)
                    vb[df][ks] = *(const bf16x8*)&Vlds[cur][(df * 32 + q31) * 64 + ((ks * 2 + hi) ^ swz) * 8];

            // ---- causal mask: only the partial tiles pay for it ----
            const bool partial = (s0 + 63 > q0);
            float pv[2][16];
            if (partial) {
#pragma unroll
                for (int kt = 0; kt < 2; ++kt)
#pragma unroll
                    for (int r = 0; r < 16; ++r) {
                        const int key = s0 + kt * 32 + (r & 3) + ((r >> 2) << 3) + hi * 4;
                        float sv = tacc[kt][r];
                        if (key > q) sv = -1e30f;
                        pv[kt][r] = sv;
                    }
            } else {
#pragma unroll
                for (int kt = 0; kt < 2; ++kt)
#pragma unroll
                    for (int r = 0; r < 16; ++r) pv[kt][r] = tacc[kt][r];
            }

            // ---- row max ----
            float rx = pv[0][0];
#pragma unroll
            for (int kt = 0; kt < 2; ++kt)
#pragma unroll
                for (int r = 0; r < 16; ++r) rx = fmaxf(rx, pv[kt][r]);
            rx = fmaxf(rx, __shfl_xor(rx, 32, 64));

            // ---- defer-max rescale (THR = 8*log2e) ----
            if (__any(rx - m > 11.5f)) {
                const float mn = fmaxf(m, rx);
                const float alpha = exp2f_fast(m - mn);
                lsum *= alpha;
                m = mn;
#pragma unroll
                for (int r = 0; r < 16; ++r) {
                    const float ar = __shfl(alpha, (r & 3) + ((r >> 2) << 3) + hi * 4, 64);
                    oacc[0][r] *= ar;
                    oacc[1][r] *= ar;
                }
            }

            // ---- exp2 + pack + row sum ----
            unsigned int pk[2][4][2];
            float rsum = 0.f;
#pragma unroll
            for (int kt = 0; kt < 2; ++kt)
#pragma unroll
                for (int g = 0; g < 4; ++g) {
                    const float e0 = exp2f_fast(pv[kt][g * 4 + 0] - m);
                    const float e1 = exp2f_fast(pv[kt][g * 4 + 1] - m);
                    const float e2 = exp2f_fast(pv[kt][g * 4 + 2] - m);
                    const float e3 = exp2f_fast(pv[kt][g * 4 + 3] - m);
                    pk[kt][g][0] = cvtpk(e0, e1);
                    pk[kt][g][1] = cvtpk(e2, e3);
                    rsum += (e0 + e1) + (e2 + e3);
                }
            rsum += __shfl_xor(rsum, 32, 64);
            lsum += rsum;

            // ---- PV: select-based PA assembly (shfl half-swap, verified) ----
#pragma unroll
            for (int ks = 0; ks < 4; ++ks) {
                const int kt = ks >> 1, kslo = ks & 1;
                const unsigned int pkA0 = pk[kt][2 * kslo][0],     pkA1 = pk[kt][2 * kslo][1];
                const unsigned int pkB0 = pk[kt][2 * kslo + 1][0], pkB1 = pk[kt][2 * kslo + 1][1];
                const unsigned int send0 = hi ? pkA0 : pkB0;
                const unsigned int send1 = hi ? pkA1 : pkB1;
                const unsigned int own0  = hi ? pkB0 : pkA0;
                const unsigned int own1  = hi ? pkB1 : pkA1;
                const unsigned int recv0 = (unsigned int)__shfl_xor((int)send0, 32, 64);
                const unsigned int recv1 = (unsigned int)__shfl_xor((int)send1, 32, 64);
                u32x4 u;
                u[0] = hi ? recv0 : own0;
                u[1] = hi ? recv1 : own1;
                u[2] = hi ? own0 : recv0;
                u[3] = hi ? own1 : recv1;
                const bf16x8 pa = __builtin_bit_cast(bf16x8, u);
                __builtin_amdgcn_s_setprio(1);
                oacc[0] = mfma32(pa, vb[0][ks], oacc[0]);
                oacc[1] = mfma32(pa, vb[1][ks], oacc[1]);
                __builtin_amdgcn_s_setprio(0);
            }
        }
        cur ^= 1;
    }
#undef STAGE

    // ---- epilogue: O /= l ----
    const float linv = 1.f / lsum;
#pragma unroll
    for (int r = 0; r < 16; ++r) {
        const int qrow = (r & 3) + ((r >> 2) << 3) + hi * 4;
        const float lr = __shfl(linv, qrow, 64);
        const int row = q0 + qrow;
        aout[(size_t)(b * S + row) * 1024 + h * 64 + q31]      = f2bf(oacc[0][r] * lr);
        aout[(size_t)(b * S + row) * 1024 + h * 64 + 32 + q31] = f2bf(oacc[1][r] * lr);
    }
}

extern "C" void kernel_launch(void* const* d_in, const int* in_sizes, int n_in,
                              void* d_out, int out_size, void* d_ws, size_t ws_size,
                              hipStream_t stream) {
    (void)in_sizes; (void)n_in; (void)out_size; (void)ws_size;
    const float* hs    = (const float*)d_in[0];  // [2,2048,1024]
    const float* wqkv  = (const float*)d_in[1];  // [1024,3072]
    const float* bqkv  = (const float*)d_in[2];  // [3072]
    const float* wproj = (const float*)d_in[3];  // [1024,1024]
    const float* bproj = (const float*)d_in[4];  // [1024]
    float* out = (float*)d_out;                  // [2,2048,1024] f32

    unsigned short* Xb  = (unsigned short*)d_ws;                 // 4096*1024 (reused as Vt)
    unsigned short* Wqt = Xb  + (size_t)4096 * 1024;             // 3072*1024
    unsigned short* Wpt = Wqt + (size_t)3072 * 1024;             // 1024*1024
    unsigned short* QKV = Wpt + (size_t)1024 * 1024;             // 4096*3072
    unsigned short* AO  = QKV + (size_t)4096 * 3072;             // 4096*1024
    unsigned short* Vt  = Xb;  // X dead after QKV GEMM; Vt = [32 bh][64 d][2048 s]

    const float qscale = 0.125f * 1.4426950408889634f;  // fold softmax scale + log2e into Q

    convert_bf16<<<4096, 256, 0, stream>>>(hs, Xb, 4096 * 1024);
    transpose_convert<<<dim3(3072 / 32, 1024 / 32), 256, 0, stream>>>(wqkv, Wqt, 1024, 3072);
    transpose_convert<<<dim3(1024 / 32, 1024 / 32), 256, 0, stream>>>(wproj, Wpt, 1024, 1024);

    gemm_bt<0><<<dim3(32, 24), 256, 0, stream>>>(Xb, Wqt, bqkv, (void*)QKV, 4096, 3072, 1024,
                                                 1024, qscale);
    transpose_v<<<dim3(64, 2, 32), 256, 0, stream>>>(QKV, Vt);
    attn_fwd8<<<dim3(16, 32), 256, 0, stream>>>(QKV, Vt, AO);
    gemm_bt<1><<<dim3(32, 8), 256, 0, stream>>>(AO, Wpt, bproj, (void*)out, 4096, 1024, 1024,
                                                0, 1.0f);
}